// Round 3
// baseline (489.740 us; speedup 1.0000x reference)
//
#include <hip/hip_runtime.h>
#include <math.h>

#define N_NODES_C 50000
#define N_EDGES_C 200000
#define FDIM 128
#define NRBF 20
#define CUT 5.0f

// ---------------------------------------------------------------------------
// Fused node MLP: phi = silu(s@W1 + b1) @ W2 + b2        (per 32-node tile)
// ---------------------------------------------------------------------------
__global__ __launch_bounds__(256) void mlp_kernel(
    const float* __restrict__ s, const float* __restrict__ W1,
    const float* __restrict__ b1, const float* __restrict__ W2,
    const float* __restrict__ b2, float* __restrict__ phi)
{
    __shared__ float sT[128 * 36];   // s tile transposed [k][node], pad to 36
    __shared__ float hT[128 * 36];   // h tile transposed [k][node]
    __shared__ float wl[16 * 384];   // weight chunk: [32][128] (A) or [16][384] (B)

    const int tid = threadIdx.x;
    const int nb  = blockIdx.x * 32;

#pragma unroll
    for (int j = 0; j < 4; ++j) {
        int fi   = tid + j * 256;
        int node = fi >> 5;
        int kq   = fi & 31;
        int gn   = nb + node; if (gn >= N_NODES_C) gn = N_NODES_C - 1;
        float4 val = *(const float4*)(s + (size_t)gn * FDIM + kq * 4);
        sT[(kq * 4 + 0) * 36 + node] = val.x;
        sT[(kq * 4 + 1) * 36 + node] = val.y;
        sT[(kq * 4 + 2) * 36 + node] = val.z;
        sT[(kq * 4 + 3) * 36 + node] = val.w;
    }

    const int tn = tid >> 5;
    const int tc = tid & 31;
    const int n0 = tn * 4;

    float acc[4][4];
#pragma unroll
    for (int i = 0; i < 4; ++i)
#pragma unroll
        for (int j = 0; j < 4; ++j) acc[i][j] = 0.f;

    for (int kt = 0; kt < 4; ++kt) {
        __syncthreads();
#pragma unroll
        for (int j = 0; j < 4; ++j) {
            int fi = tid + j * 256;
            int row = fi >> 5;
            int cq  = fi & 31;
            *(float4*)(wl + row * 128 + cq * 4) =
                *(const float4*)(W1 + (size_t)(kt * 32 + row) * FDIM + cq * 4);
        }
        __syncthreads();
#pragma unroll
        for (int k = 0; k < 32; ++k) {
            float4 a = *(const float4*)(sT + (kt * 32 + k) * 36 + n0);
            float4 b = *(const float4*)(wl + k * 128 + tc * 4);
            float av[4] = {a.x, a.y, a.z, a.w};
            float bv[4] = {b.x, b.y, b.z, b.w};
#pragma unroll
            for (int i = 0; i < 4; ++i)
#pragma unroll
                for (int jj = 0; jj < 4; ++jj)
                    acc[i][jj] += av[i] * bv[jj];
        }
    }

    {
        float4 bb = *(const float4*)(b1 + tc * 4);
        float bbv[4] = {bb.x, bb.y, bb.z, bb.w};
#pragma unroll
        for (int i = 0; i < 4; ++i)
#pragma unroll
            for (int jj = 0; jj < 4; ++jj) {
                float h = acc[i][jj] + bbv[jj];
                h = h / (1.f + __expf(-h));
                hT[(tc * 4 + jj) * 36 + n0 + i] = h;
            }
    }

    float acc2[4][12];
#pragma unroll
    for (int i = 0; i < 4; ++i)
#pragma unroll
        for (int j = 0; j < 12; ++j) acc2[i][j] = 0.f;

    for (int kt = 0; kt < 8; ++kt) {
        __syncthreads();
#pragma unroll
        for (int j = 0; j < 6; ++j) {
            int fi = tid + j * 256;
            int row = fi / 96;
            int cq  = fi % 96;
            *(float4*)(wl + row * 384 + cq * 4) =
                *(const float4*)(W2 + (size_t)(kt * 16 + row) * 384 + cq * 4);
        }
        __syncthreads();
#pragma unroll
        for (int k = 0; k < 16; ++k) {
            float4 a = *(const float4*)(hT + (kt * 16 + k) * 36 + n0);
            float av[4] = {a.x, a.y, a.z, a.w};
#pragma unroll
            for (int p = 0; p < 3; ++p) {
                float4 b = *(const float4*)(wl + k * 384 + p * 128 + tc * 4);
                float bv[4] = {b.x, b.y, b.z, b.w};
#pragma unroll
                for (int i = 0; i < 4; ++i)
#pragma unroll
                    for (int q = 0; q < 4; ++q)
                        acc2[i][p * 4 + q] += av[i] * bv[q];
            }
        }
    }

#pragma unroll
    for (int p = 0; p < 3; ++p) {
        float4 bb = *(const float4*)(b2 + p * 128 + tc * 4);
        float bbv[4] = {bb.x, bb.y, bb.z, bb.w};
#pragma unroll
        for (int i = 0; i < 4; ++i) {
            int gn = nb + n0 + i;
            if (gn < N_NODES_C) {
                float4 o;
                o.x = acc2[i][p * 4 + 0] + bbv[0];
                o.y = acc2[i][p * 4 + 1] + bbv[1];
                o.z = acc2[i][p * 4 + 2] + bbv[2];
                o.w = acc2[i][p * 4 + 3] + bbv[3];
                *(float4*)(phi + (size_t)gn * 384 + p * 128 + tc * 4) = o;
            }
        }
    }
}

// ---------------------------------------------------------------------------
// CSR build: histogram -> scan -> fill (dst-sorted edge slots)
// ---------------------------------------------------------------------------
__global__ __launch_bounds__(256) void count_kernel(
    const int* __restrict__ dst, int* __restrict__ counts)
{
    int e = blockIdx.x * 256 + threadIdx.x;
    if (e < N_EDGES_C) atomicAdd(counts + dst[e], 1);
}

#define SCAN_T 1024
#define SCAN_CH 49   // 1024*49 = 50176 >= 50000

__global__ __launch_bounds__(SCAN_T) void scan_kernel(
    const int* __restrict__ counts, int* __restrict__ row_ptr,
    int* __restrict__ row_fill)
{
    __shared__ int psum[SCAN_T];
    const int t = threadIdx.x;
    const int base = t * SCAN_CH;

    int local[SCAN_CH];
    int ssum = 0;
#pragma unroll
    for (int i = 0; i < SCAN_CH; ++i) {
        int idx = base + i;
        int c = (idx < N_NODES_C) ? counts[idx] : 0;
        local[i] = c;
        ssum += c;
    }
    psum[t] = ssum;
    __syncthreads();

    // Hillis-Steele inclusive scan over 1024 partials
    for (int off = 1; off < SCAN_T; off <<= 1) {
        int v = psum[t];
        int add = (t >= off) ? psum[t - off] : 0;
        __syncthreads();
        psum[t] = v + add;
        __syncthreads();
    }

    int pre = psum[t] - ssum;   // exclusive prefix of this chunk
#pragma unroll
    for (int i = 0; i < SCAN_CH; ++i) {
        int idx = base + i;
        if (idx < N_NODES_C) {
            row_ptr[idx]  = pre;
            row_fill[idx] = pre;
            pre += local[i];
        }
    }
    if (t == SCAN_T - 1) row_ptr[N_NODES_C] = psum[SCAN_T - 1];
}

// ---------------------------------------------------------------------------
// Edge precompute: per edge -> dst-sorted slot with
//   e4a = (dx, dy, dz, fcut),  e4b = (sin t, cos t, invd*fcut, bitcast(src))
// ---------------------------------------------------------------------------
__global__ __launch_bounds__(256) void fill_kernel(
    const float* __restrict__ rel_pos, const int* __restrict__ src,
    const int* __restrict__ dst, int* __restrict__ row_fill,
    float4* __restrict__ e4a, float4* __restrict__ e4b)
{
    int e = blockIdx.x * 256 + threadIdx.x;
    if (e >= N_EDGES_C) return;

    int pos = atomicAdd(row_fill + dst[e], 1);

    float x = rel_pos[3 * e + 0];
    float y = rel_pos[3 * e + 1];
    float z = rel_pos[3 * e + 2];
    float d = sqrtf(x * x + y * y + z * z);
    float invd = 1.0f / d;

    float s1 = 0.f, c1 = 0.f, fcut = 0.f, amp = 0.f;
    if (d < CUT) {
        sincosf((3.14159265358979f / CUT) * d, &s1, &c1);
        fcut = 0.5f * (c1 + 1.0f);
        amp  = invd * fcut;
    }

    float4 a = {x * invd, y * invd, z * invd, fcut};
    float4 b = {s1, c1, amp, __int_as_float(src[e])};
    e4a[pos] = a;
    e4b[pos] = b;
}

// ---------------------------------------------------------------------------
// Gather kernel: per dst node, contiguous CSR range, register accumulate,
// single coalesced store.
// ---------------------------------------------------------------------------
__global__ __launch_bounds__(256) void gather_kernel(
    const float* __restrict__ v, const float* __restrict__ Wr,
    const float* __restrict__ br, const int* __restrict__ row_ptr,
    const float4* __restrict__ e4a, const float4* __restrict__ e4b,
    const float* __restrict__ phi, float* __restrict__ out_v,
    float* __restrict__ out_s)
{
    __shared__ float wr_l[NRBF * 384];
    __shared__ float br_l[384];

    for (int i = threadIdx.x; i < NRBF * 384; i += 256) wr_l[i] = Wr[i];
    for (int i = threadIdx.x; i < 384; i += 256) br_l[i] = br[i];
    __syncthreads();

    const int grp = threadIdx.x >> 7;    // 2 dst nodes per block
    const int f   = threadIdx.x & 127;
    const int n   = blockIdx.x * 2 + grp;

    const int beg = row_ptr[n];
    const int end = row_ptr[n + 1];

    float acc_s = 0.f, acc_v0 = 0.f, acc_v1 = 0.f, acc_v2 = 0.f;

    for (int idx = beg; idx < end; ++idx) {
        float4 ea = e4a[idx];
        float4 eb = e4b[idx];
        int si = __float_as_int(eb.w);

        const float* ph = phi + (size_t)si * 384;
        const float* vr = v   + (size_t)si * 384;
        float pv0 = ph[f];
        float pv1 = ph[128 + f];
        float pv2 = ph[256 + f];
        float vv0 = vr[f];
        float vv1 = vr[128 + f];
        float vv2 = vr[256 + f];

        const float s1 = eb.x, c1 = eb.y, amp = eb.z;
        float sk = s1, ck = c1;
        float a0 = 0.f, a1 = 0.f, a2 = 0.f;
#pragma unroll
        for (int k = 0; k < NRBF; ++k) {
            float rb = sk * amp;
            a0 += rb * wr_l[k * 384 + f];
            a1 += rb * wr_l[k * 384 + 128 + f];
            a2 += rb * wr_l[k * 384 + 256 + f];
            float sn = sk * c1 + ck * s1;
            ck = ck * c1 - sk * s1;
            sk = sn;
        }
        float w0 = a0 + br_l[f] * ea.w;
        float w1 = a1 + br_l[128 + f] * ea.w;
        float w2 = a2 + br_l[256 + f] * ea.w;

        float sv = w0 * pv0;
        float ss = w1 * pv1;
        float sr = w2 * pv2;

        acc_s  += ss;
        acc_v0 += vv0 * sv + ea.x * sr;
        acc_v1 += vv1 * sv + ea.y * sr;
        acc_v2 += vv2 * sv + ea.z * sr;
    }

    out_s[(size_t)n * 128 + f] = acc_s;
    out_v[(size_t)n * 384 +       f] = acc_v0;
    out_v[(size_t)n * 384 + 128 + f] = acc_v1;
    out_v[(size_t)n * 384 + 256 + f] = acc_v2;
}

// ---------------------------------------------------------------------------
extern "C" void kernel_launch(void* const* d_in, const int* in_sizes, int n_in,
                              void* d_out, int out_size, void* d_ws, size_t ws_size,
                              hipStream_t stream)
{
    const float* s  = (const float*)d_in[0];
    const float* v  = (const float*)d_in[1];
    const float* rp = (const float*)d_in[2];
    const float* W1 = (const float*)d_in[3];
    const float* b1 = (const float*)d_in[4];
    const float* W2 = (const float*)d_in[5];
    const float* b2 = (const float*)d_in[6];
    const float* Wr = (const float*)d_in[7];
    const float* br = (const float*)d_in[8];
    const int* src  = (const int*)d_in[9];
    const int* dst  = (const int*)d_in[10];

    float* out   = (float*)d_out;
    float* out_v = out;                                    // 50000*3*128
    float* out_s = out + (size_t)N_NODES_C * 3 * FDIM;     // 50000*128

    // workspace layout (16B-aligned pieces first)
    char* ws = (char*)d_ws;
    float*  phi  = (float*)ws;                    ws += (size_t)N_NODES_C * 384 * sizeof(float);
    float4* e4a  = (float4*)ws;                   ws += (size_t)N_EDGES_C * sizeof(float4);
    float4* e4b  = (float4*)ws;                   ws += (size_t)N_EDGES_C * sizeof(float4);
    int* counts   = (int*)ws;                     ws += (size_t)N_NODES_C * sizeof(int);
    int* row_ptr  = (int*)ws;                     ws += (size_t)(N_NODES_C + 1) * sizeof(int);
    int* row_fill = (int*)ws;

    hipMemsetAsync(counts, 0, (size_t)N_NODES_C * sizeof(int), stream);

    count_kernel<<<(N_EDGES_C + 255) / 256, 256, 0, stream>>>(dst, counts);
    scan_kernel<<<1, SCAN_T, 0, stream>>>(counts, row_ptr, row_fill);
    fill_kernel<<<(N_EDGES_C + 255) / 256, 256, 0, stream>>>(rp, src, dst, row_fill, e4a, e4b);
    mlp_kernel<<<(N_NODES_C + 31) / 32, 256, 0, stream>>>(s, W1, b1, W2, b2, phi);
    gather_kernel<<<N_NODES_C / 2, 256, 0, stream>>>(v, Wr, br, row_ptr, e4a, e4b,
                                                     phi, out_v, out_s);
}

// Round 4
// 404.393 us; speedup vs baseline: 1.2111x; 1.2111x over previous
//
#include <hip/hip_runtime.h>
#include <math.h>

#define N_NODES_C 50000
#define N_EDGES_C 200000
#define FDIM 128
#define NRBF 20
#define CUT 5.0f
#define SC_BLK 196   // ceil(50000/256)

__device__ __forceinline__ unsigned short f32_to_bf16(float f) {
    unsigned u = __float_as_uint(f);
    unsigned r = (u + 0x7FFFu + ((u >> 16) & 1u)) >> 16;   // RNE
    return (unsigned short)r;
}
__device__ __forceinline__ float bf16_to_f32(unsigned short h) {
    return __uint_as_float(((unsigned)h) << 16);
}

// ---------------------------------------------------------------------------
// Fused node MLP: phi = silu(s@W1 + b1) @ W2 + b2   (bf16 output)
// ---------------------------------------------------------------------------
__global__ __launch_bounds__(256) void mlp_kernel(
    const float* __restrict__ s, const float* __restrict__ W1,
    const float* __restrict__ b1, const float* __restrict__ W2,
    const float* __restrict__ b2, unsigned short* __restrict__ phi)
{
    __shared__ float sT[128 * 36];
    __shared__ float hT[128 * 36];
    __shared__ float wl[16 * 384];

    const int tid = threadIdx.x;
    const int nb  = blockIdx.x * 32;

#pragma unroll
    for (int j = 0; j < 4; ++j) {
        int fi   = tid + j * 256;
        int node = fi >> 5;
        int kq   = fi & 31;
        int gn   = nb + node; if (gn >= N_NODES_C) gn = N_NODES_C - 1;
        float4 val = *(const float4*)(s + (size_t)gn * FDIM + kq * 4);
        sT[(kq * 4 + 0) * 36 + node] = val.x;
        sT[(kq * 4 + 1) * 36 + node] = val.y;
        sT[(kq * 4 + 2) * 36 + node] = val.z;
        sT[(kq * 4 + 3) * 36 + node] = val.w;
    }

    const int tn = tid >> 5;
    const int tc = tid & 31;
    const int n0 = tn * 4;

    float acc[4][4];
#pragma unroll
    for (int i = 0; i < 4; ++i)
#pragma unroll
        for (int j = 0; j < 4; ++j) acc[i][j] = 0.f;

    for (int kt = 0; kt < 4; ++kt) {
        __syncthreads();
#pragma unroll
        for (int j = 0; j < 4; ++j) {
            int fi = tid + j * 256;
            int row = fi >> 5;
            int cq  = fi & 31;
            *(float4*)(wl + row * 128 + cq * 4) =
                *(const float4*)(W1 + (size_t)(kt * 32 + row) * FDIM + cq * 4);
        }
        __syncthreads();
#pragma unroll
        for (int k = 0; k < 32; ++k) {
            float4 a = *(const float4*)(sT + (kt * 32 + k) * 36 + n0);
            float4 b = *(const float4*)(wl + k * 128 + tc * 4);
            float av[4] = {a.x, a.y, a.z, a.w};
            float bv[4] = {b.x, b.y, b.z, b.w};
#pragma unroll
            for (int i = 0; i < 4; ++i)
#pragma unroll
                for (int jj = 0; jj < 4; ++jj)
                    acc[i][jj] += av[i] * bv[jj];
        }
    }

    {
        float4 bb = *(const float4*)(b1 + tc * 4);
        float bbv[4] = {bb.x, bb.y, bb.z, bb.w};
#pragma unroll
        for (int i = 0; i < 4; ++i)
#pragma unroll
            for (int jj = 0; jj < 4; ++jj) {
                float h = acc[i][jj] + bbv[jj];
                h = h / (1.f + __expf(-h));
                hT[(tc * 4 + jj) * 36 + n0 + i] = h;
            }
    }

    float acc2[4][12];
#pragma unroll
    for (int i = 0; i < 4; ++i)
#pragma unroll
        for (int j = 0; j < 12; ++j) acc2[i][j] = 0.f;

    for (int kt = 0; kt < 8; ++kt) {
        __syncthreads();
#pragma unroll
        for (int j = 0; j < 6; ++j) {
            int fi = tid + j * 256;
            int row = fi / 96;
            int cq  = fi % 96;
            *(float4*)(wl + row * 384 + cq * 4) =
                *(const float4*)(W2 + (size_t)(kt * 16 + row) * 384 + cq * 4);
        }
        __syncthreads();
#pragma unroll
        for (int k = 0; k < 16; ++k) {
            float4 a = *(const float4*)(hT + (kt * 16 + k) * 36 + n0);
            float av[4] = {a.x, a.y, a.z, a.w};
#pragma unroll
            for (int p = 0; p < 3; ++p) {
                float4 b = *(const float4*)(wl + k * 384 + p * 128 + tc * 4);
                float bv[4] = {b.x, b.y, b.z, b.w};
#pragma unroll
                for (int i = 0; i < 4; ++i)
#pragma unroll
                    for (int q = 0; q < 4; ++q)
                        acc2[i][p * 4 + q] += av[i] * bv[q];
            }
        }
    }

#pragma unroll
    for (int p = 0; p < 3; ++p) {
        float4 bb = *(const float4*)(b2 + p * 128 + tc * 4);
        float bbv[4] = {bb.x, bb.y, bb.z, bb.w};
#pragma unroll
        for (int i = 0; i < 4; ++i) {
            int gn = nb + n0 + i;
            if (gn < N_NODES_C) {
                ushort4 o;
                o.x = f32_to_bf16(acc2[i][p * 4 + 0] + bbv[0]);
                o.y = f32_to_bf16(acc2[i][p * 4 + 1] + bbv[1]);
                o.z = f32_to_bf16(acc2[i][p * 4 + 2] + bbv[2]);
                o.w = f32_to_bf16(acc2[i][p * 4 + 3] + bbv[3]);
                *(ushort4*)(phi + (size_t)gn * 384 + p * 128 + tc * 4) = o;
            }
        }
    }
}

// ---------------------------------------------------------------------------
// CSR build: histogram -> 3-kernel parallel scan -> fill
// ---------------------------------------------------------------------------
__global__ __launch_bounds__(256) void count_kernel(
    const int* __restrict__ dst, int* __restrict__ counts)
{
    int e = blockIdx.x * 256 + threadIdx.x;
    if (e < N_EDGES_C) atomicAdd(counts + dst[e], 1);
}

__global__ __launch_bounds__(256) void scan1_kernel(
    const int* __restrict__ counts, int* __restrict__ row_tmp,
    int* __restrict__ partial)
{
    __shared__ int sm[256];
    const int t = threadIdx.x;
    const int idx = blockIdx.x * 256 + t;
    int c = (idx < N_NODES_C) ? counts[idx] : 0;
    int x = c;
    sm[t] = x;
    __syncthreads();
#pragma unroll
    for (int off = 1; off < 256; off <<= 1) {
        int y = (t >= off) ? sm[t - off] : 0;
        __syncthreads();
        x += y;
        sm[t] = x;
        __syncthreads();
    }
    if (idx < N_NODES_C) row_tmp[idx] = x - c;     // exclusive within block
    if (t == 255) partial[blockIdx.x] = x;         // block total
}

__global__ __launch_bounds__(256) void scan2_kernel(
    const int* __restrict__ partial, int* __restrict__ poffs)
{
    __shared__ int sm[256];
    const int t = threadIdx.x;
    int c = (t < SC_BLK) ? partial[t] : 0;
    int x = c;
    sm[t] = x;
    __syncthreads();
#pragma unroll
    for (int off = 1; off < 256; off <<= 1) {
        int y = (t >= off) ? sm[t - off] : 0;
        __syncthreads();
        x += y;
        sm[t] = x;
        __syncthreads();
    }
    if (t < SC_BLK) poffs[t] = x - c;              // exclusive block offset
}

__global__ __launch_bounds__(256) void scan3_kernel(
    const int* __restrict__ row_tmp, const int* __restrict__ poffs,
    int* __restrict__ row_ptr, int* __restrict__ row_fill)
{
    const int idx = blockIdx.x * 256 + threadIdx.x;
    if (idx < N_NODES_C) {
        int rp = row_tmp[idx] + poffs[blockIdx.x];
        row_ptr[idx]  = rp;
        row_fill[idx] = rp;
    }
    if (idx == 0) row_ptr[N_NODES_C] = N_EDGES_C;
}

// ---------------------------------------------------------------------------
// Edge precompute into dst-sorted slots:
//   e4a[pos] = (dx, dy, dz, fcut)
//   e_rbf[pos][k] = sin((k+1)*pi*d/CUT) * invd * fcut   (k = 0..19)
//   esrc[pos] = src
// ---------------------------------------------------------------------------
__global__ __launch_bounds__(256) void fill_kernel(
    const float* __restrict__ rel_pos, const int* __restrict__ src,
    const int* __restrict__ dst, int* __restrict__ row_fill,
    float4* __restrict__ e4a, float* __restrict__ e_rbf,
    int* __restrict__ esrc)
{
    int e = blockIdx.x * 256 + threadIdx.x;
    if (e >= N_EDGES_C) return;

    int pos = atomicAdd(row_fill + dst[e], 1);

    float x = rel_pos[3 * e + 0];
    float y = rel_pos[3 * e + 1];
    float z = rel_pos[3 * e + 2];
    float d = sqrtf(x * x + y * y + z * z);
    float invd = 1.0f / d;

    float s1 = 0.f, c1 = 0.f, fcut = 0.f, amp = 0.f;
    if (d < CUT) {
        sincosf((3.14159265358979f / CUT) * d, &s1, &c1);
        fcut = 0.5f * (c1 + 1.0f);
        amp  = invd * fcut;
    }

    float4 a = {x * invd, y * invd, z * invd, fcut};
    e4a[pos] = a;
    esrc[pos] = src[e];

    float* rb = e_rbf + (size_t)pos * NRBF;
    float sk = s1, ck = c1;
#pragma unroll
    for (int k = 0; k < NRBF; ++k) {
        rb[k] = sk * amp;
        float sn = sk * c1 + ck * s1;
        ck = ck * c1 - sk * s1;
        sk = sn;
    }
}

// ---------------------------------------------------------------------------
// Gather kernel: Wr in registers (no LDS), precomputed per-edge RBF,
// contiguous CSR walk, register accumulate, single coalesced store.
// ---------------------------------------------------------------------------
__global__ __launch_bounds__(256) void gather_kernel(
    const float* __restrict__ v, const float* __restrict__ Wr,
    const float* __restrict__ br, const int* __restrict__ row_ptr,
    const float4* __restrict__ e4a, const float* __restrict__ e_rbf,
    const int* __restrict__ esrc, const unsigned short* __restrict__ phi,
    float* __restrict__ out_v, float* __restrict__ out_s)
{
    const int grp = threadIdx.x >> 7;      // 2 dst nodes per block
    const int f   = threadIdx.x & 127;
    const int n   = blockIdx.x * 2 + grp;

    // per-lane Wr column weights (fixed by f) -> registers
    float wr0[NRBF], wr1[NRBF], wr2[NRBF];
#pragma unroll
    for (int k = 0; k < NRBF; ++k) {
        wr0[k] = Wr[k * 384 +       f];
        wr1[k] = Wr[k * 384 + 128 + f];
        wr2[k] = Wr[k * 384 + 256 + f];
    }
    const float br0 = br[f], br1 = br[128 + f], br2 = br[256 + f];

    const int beg = row_ptr[n];
    const int end = row_ptr[n + 1];

    float acc_s = 0.f, acc_v0 = 0.f, acc_v1 = 0.f, acc_v2 = 0.f;

    for (int idx = beg; idx < end; ++idx) {
        float4 ea = e4a[idx];
        int si = esrc[idx];

        const float* rbp = e_rbf + (size_t)idx * NRBF;
        float4 r0 = *(const float4*)(rbp + 0);
        float4 r1 = *(const float4*)(rbp + 4);
        float4 r2 = *(const float4*)(rbp + 8);
        float4 r3 = *(const float4*)(rbp + 12);
        float4 r4 = *(const float4*)(rbp + 16);
        float rr[NRBF] = {r0.x, r0.y, r0.z, r0.w, r1.x, r1.y, r1.z, r1.w,
                          r2.x, r2.y, r2.z, r2.w, r3.x, r3.y, r3.z, r3.w,
                          r4.x, r4.y, r4.z, r4.w};

        const unsigned short* ph = phi + (size_t)si * 384;
        const float*          vr = v   + (size_t)si * 384;
        float pv0 = bf16_to_f32(ph[f]);
        float pv1 = bf16_to_f32(ph[128 + f]);
        float pv2 = bf16_to_f32(ph[256 + f]);
        float vv0 = vr[f];
        float vv1 = vr[128 + f];
        float vv2 = vr[256 + f];

        float w0 = br0 * ea.w, w1 = br1 * ea.w, w2 = br2 * ea.w;
#pragma unroll
        for (int k = 0; k < NRBF; ++k) {
            w0 += rr[k] * wr0[k];
            w1 += rr[k] * wr1[k];
            w2 += rr[k] * wr2[k];
        }

        float sv = w0 * pv0;
        float ss = w1 * pv1;
        float sr = w2 * pv2;

        acc_s  += ss;
        acc_v0 += vv0 * sv + ea.x * sr;
        acc_v1 += vv1 * sv + ea.y * sr;
        acc_v2 += vv2 * sv + ea.z * sr;
    }

    out_s[(size_t)n * 128 + f] = acc_s;
    out_v[(size_t)n * 384 +       f] = acc_v0;
    out_v[(size_t)n * 384 + 128 + f] = acc_v1;
    out_v[(size_t)n * 384 + 256 + f] = acc_v2;
}

// ---------------------------------------------------------------------------
extern "C" void kernel_launch(void* const* d_in, const int* in_sizes, int n_in,
                              void* d_out, int out_size, void* d_ws, size_t ws_size,
                              hipStream_t stream)
{
    const float* s  = (const float*)d_in[0];
    const float* v  = (const float*)d_in[1];
    const float* rp = (const float*)d_in[2];
    const float* W1 = (const float*)d_in[3];
    const float* b1 = (const float*)d_in[4];
    const float* W2 = (const float*)d_in[5];
    const float* b2 = (const float*)d_in[6];
    const float* Wr = (const float*)d_in[7];
    const float* br = (const float*)d_in[8];
    const int* src  = (const int*)d_in[9];
    const int* dst  = (const int*)d_in[10];

    float* out   = (float*)d_out;
    float* out_v = out;                                    // 50000*3*128
    float* out_s = out + (size_t)N_NODES_C * 3 * FDIM;     // 50000*128

    // workspace layout (16B-aligned pieces first)
    char* ws = (char*)d_ws;
    unsigned short* phi = (unsigned short*)ws;    ws += (size_t)N_NODES_C * 384 * sizeof(unsigned short);
    float4* e4a   = (float4*)ws;                  ws += (size_t)N_EDGES_C * sizeof(float4);
    float*  e_rbf = (float*)ws;                   ws += (size_t)N_EDGES_C * NRBF * sizeof(float);
    int* esrc     = (int*)ws;                     ws += (size_t)N_EDGES_C * sizeof(int);
    int* counts   = (int*)ws;                     ws += (size_t)N_NODES_C * sizeof(int);
    int* row_ptr  = (int*)ws;                     ws += (size_t)(N_NODES_C + 1) * sizeof(int);
    int* row_fill = (int*)ws;                     ws += (size_t)N_NODES_C * sizeof(int);
    int* row_tmp  = (int*)ws;                     ws += (size_t)N_NODES_C * sizeof(int);
    int* partial  = (int*)ws;                     ws += (size_t)256 * sizeof(int);
    int* poffs    = (int*)ws;

    hipMemsetAsync(counts, 0, (size_t)N_NODES_C * sizeof(int), stream);

    count_kernel<<<(N_EDGES_C + 255) / 256, 256, 0, stream>>>(dst, counts);
    scan1_kernel<<<SC_BLK, 256, 0, stream>>>(counts, row_tmp, partial);
    scan2_kernel<<<1, 256, 0, stream>>>(partial, poffs);
    scan3_kernel<<<SC_BLK, 256, 0, stream>>>(row_tmp, poffs, row_ptr, row_fill);
    fill_kernel<<<(N_EDGES_C + 255) / 256, 256, 0, stream>>>(rp, src, dst, row_fill,
                                                             e4a, e_rbf, esrc);
    mlp_kernel<<<(N_NODES_C + 31) / 32, 256, 0, stream>>>(s, W1, b1, W2, b2, phi);
    gather_kernel<<<N_NODES_C / 2, 256, 0, stream>>>(v, Wr, br, row_ptr, e4a, e_rbf,
                                                     esrc, phi, out_v, out_s);
}